// Round 1
// baseline (305.002 us; speedup 1.0000x reference)
//
#include <hip/hip_runtime.h>
#include <stdint.h>

typedef unsigned short u16;
typedef __bf16 bf16x8 __attribute__((ext_vector_type(8)));
typedef float f32x4 __attribute__((ext_vector_type(4)));

typedef const __attribute__((address_space(1))) void* gptr_t;
typedef __attribute__((address_space(3))) void* sptr_t;

// ---- sizes ----
// x: (32,256,56,56) f32, W: (256,256,3,3) f32, out: (32,256,28,28) f32
#define M_TOTAL    100352          // 32*56*56
#define XPAD_BYTES 55115776L       // 32*58*58*256 * 2
#define WPACK_OFF  55115776L
#define Y_OFF      56295424L       // + 9*256*256*2 = 1179648
#define STATS_OFF  107675648L      // + 32*56*56*256*2 = 51380224

__device__ __forceinline__ u16 f32_bf16(float f) {
  uint32_t u = __float_as_uint(f);
  u += 0x7FFFu + ((u >> 16) & 1u);
  return (u16)(u >> 16);
}
__device__ __forceinline__ float bf16_f32(u16 h) {
  return __uint_as_float(((uint32_t)h) << 16);
}
__device__ __forceinline__ void gload_lds16(const void* g, void* l) {
  __builtin_amdgcn_global_load_lds((gptr_t)g, (sptr_t)l, 16, 0, 0);
}

// ---- binarize + pack W:  wp[((f*8+kc)*4+ks)*2048 + co*8 + e] = sign(W[co][ci][kh][kw])
//      where f=kh*3+kw, ci = kc*32 + ks*8 + e  (B operand [K][co] in 8-k slices)
__global__ void prep_w(const float* __restrict__ W, u16* __restrict__ wp) {
  int idx = blockIdx.x * 256 + threadIdx.x;       // 0..589823
  int e  = idx & 7;
  int co = (idx >> 3) & 255;
  int ks = idx >> 11;                             // f*32 + (ci>>3)
  int f  = ks >> 5;
  int ci = ((ks & 31) << 3) | e;
  int kh = (f * 11) >> 5;                         // f/3 for f in 0..8
  int kw = f - kh * 3;
  float v = W[((co * 256 + ci) * 3 + kh) * 3 + kw];
  wp[idx] = (u16)(0x3F80u | ((__float_as_uint(v) >> 16) & 0x8000u));
}

// ---- NCHW f32 -> padded NHWC bf16  (x_pad[32][58][58][256], borders pre-zeroed by memset)
__global__ void prep_x(const float* __restrict__ x, u16* __restrict__ xp) {
  int b = blockIdx.x;                 // (n*56 + h)*4 + cblk
  int cblk = b & 3;
  int nh = b >> 2;
  int h = nh % 56, n = nh / 56;
  __shared__ float tile[64][57];
  int tid = threadIdx.x;
  const float* src = x + (((long)n * 256 + cblk * 64) * 56 + h) * 56;
#pragma unroll
  for (int i = 0; i < 14; ++i) {
    int idx = i * 256 + tid;          // 0..3583
    int c = idx / 56, wq = idx - c * 56;
    tile[c][wq] = src[(long)c * 3136 + wq];
  }
  __syncthreads();
  u16* dst = xp + (((long)n * 58 + (h + 1)) * 58 + 1) * 256 + cblk * 64;
#pragma unroll
  for (int i = 0; i < 14; ++i) {
    int idx = i * 256 + tid;
    int c = idx & 63, wq = idx >> 6;  // wq 0..55
    dst[(long)wq * 256 + c] = f32_bf16(tile[c][wq]);
  }
}

// ---- implicit-GEMM conv: y[M][256] bf16 NHWC; per-channel sum/sumsq via atomics ----
__global__ __launch_bounds__(256) void conv_gemm(
    const u16* __restrict__ xp, const u16* __restrict__ wp,
    u16* __restrict__ y, float* __restrict__ stats) {
  __shared__ __align__(16) u16 As[2][4][128][8];   // [buf][kslot][row][8k]
  __shared__ __align__(16) u16 Bs[2][4][128][8];   // [buf][kslot][co][8k]

  const int tid = threadIdx.x;
  const int w = tid >> 6, l = tid & 63;
  const int bid = blockIdx.x;
  const int gm = bid >> 1, gn = bid & 1;           // 784 x 2

  // A staging: this thread owns one output row for both gload issues
  const int rA = ((w & 1) << 6) + l;
  const int gr = gm * 128 + rA;
  const int n   = gr / 3136;
  const int rem = gr - n * 3136;
  const int hh  = rem / 56;
  const int wx  = rem - hh * 56;
  const long rowbase = (((long)n * 58 + hh) * 58 + wx) * 256;
  const u16* gA = xp + rowbase + (w >> 1) * 8;
  const u16* gB = wp + ((long)((w >> 1) * 256 + gn * 128 + ((w & 1) << 6) + l)) * 8;
  u16* ldsA = &As[0][0][0][0] + w * 512;           // chunk = issue*4 + w (1024B chunks)
  u16* ldsB = &Bs[0][0][0][0] + w * 512;
  const int bufStride = 4 * 128 * 8;               // 4096 u16 per buffer

  // fragment read coords
  const int lane16 = l & 15, lk = l >> 4;
  const int rowA0 = ((w >> 1) << 6) + lane16;
  const int colB0 = ((w & 1) << 6) + lane16;

  f32x4 acc[4][4] = {};

  auto stage = [&](int buf, int t) {
    const int f = t >> 3, kc = t & 7;              // t = f*8 + kc, 72 steps
    const int kh = (f * 11) >> 5;
    const int kw = f - kh * 3;
    const int aoff = (kh * 58 + kw) * 256 + kc * 32;
    const u16* ga = gA + aoff;
    const u16* gb = gB + (long)t * 8192;
    u16* la = ldsA + buf * bufStride;
    u16* lb = ldsB + buf * bufStride;
    gload_lds16(ga,        la);                    // issue0: kslot w>>1,   rows (w&1)*64+l
    gload_lds16(ga + 16,   la + 2048);             // issue1: kslot w>>1+2
    gload_lds16(gb,        lb);
    gload_lds16(gb + 4096, lb + 2048);
  };

  stage(0, 0);
  __syncthreads();

  int buf = 0;
  for (int t = 0; t < 72; ++t) {
    if (t + 1 < 72) stage(buf ^ 1, t + 1);
    bf16x8 av[4], bv[4];
#pragma unroll
    for (int mf = 0; mf < 4; ++mf)
      av[mf] = *(const bf16x8*)&As[buf][lk][rowA0 + mf * 16][0];
#pragma unroll
    for (int nf = 0; nf < 4; ++nf)
      bv[nf] = *(const bf16x8*)&Bs[buf][lk][colB0 + nf * 16][0];
#pragma unroll
    for (int mf = 0; mf < 4; ++mf)
#pragma unroll
      for (int nf = 0; nf < 4; ++nf)
        acc[mf][nf] = __builtin_amdgcn_mfma_f32_16x16x32_bf16(av[mf], bv[nf], acc[mf][nf], 0, 0, 0);
    __syncthreads();
    buf ^= 1;
  }

  // per-channel partial sums (rows of this wave) -> atomics
  const int colbase = gn * 128 + ((w & 1) << 6);
#pragma unroll
  for (int nf = 0; nf < 4; ++nf) {
    float s = 0.f, q = 0.f;
#pragma unroll
    for (int mf = 0; mf < 4; ++mf)
#pragma unroll
      for (int j = 0; j < 4; ++j) {
        float v = acc[mf][nf][j];
        s += v; q += v * v;
      }
    s += __shfl_xor(s, 16, 64);
    s += __shfl_xor(s, 32, 64);
    q += __shfl_xor(q, 16, 64);
    q += __shfl_xor(q, 32, 64);
    if (lk == 0) {
      atomicAdd(&stats[colbase + nf * 16 + lane16], s);
      atomicAdd(&stats[256 + colbase + nf * 16 + lane16], q);
    }
  }

  // store y bf16 NHWC: row = gm*128 + wm*64 + mf*16 + lk*4 + j ; col = colbase + nf*16 + lane16
  const long rowY = (long)gm * 128 + ((w >> 1) << 6);
#pragma unroll
  for (int mf = 0; mf < 4; ++mf)
#pragma unroll
    for (int j = 0; j < 4; ++j) {
      long r = rowY + mf * 16 + lk * 4 + j;
      u16* dst = y + r * 256 + colbase + lane16;
#pragma unroll
      for (int nf = 0; nf < 4; ++nf)
        dst[nf * 16] = f32_bf16(acc[mf][nf][j]);
    }
}

// ---- finalize BN coefficients: scale = gamma*rsqrt(var+eps), shift = beta - mean*scale
__global__ void bn_stats(const float* __restrict__ stats, const float* __restrict__ gamma,
                         const float* __restrict__ beta, float* __restrict__ sc) {
  int c = threadIdx.x;
  const float inv = 1.0f / (float)M_TOTAL;
  float mean = stats[c] * inv;
  float var  = stats[256 + c] * inv - mean * mean;
  float s = gamma[c] * rsqrtf(var + 1e-5f);
  float b = beta[c] - mean * s;
  sc[c] = s;
  sc[256 + c] = b;
}

// ---- fused BN + ReLU + 2x2 maxpool, NHWC bf16 -> NCHW f32 ----
__global__ void bn_pool(const u16* __restrict__ y, const float* __restrict__ sc,
                        float* __restrict__ out) {
  int b = blockIdx.x;                 // n*28 + ho
  int ho = b % 28, n = b / 28;
  __shared__ u16 t[256][113];         // [co][h2*56+wq], pad to break conflicts
  __shared__ float ssc[256], ssb[256];
  int tid = threadIdx.x;
  ssc[tid] = sc[tid];
  ssb[tid] = sc[256 + tid];
  const u16* src = y + (((long)n * 56 + ho * 2) * 56) * 256;
#pragma unroll
  for (int i = 0; i < 14; ++i) {
    int v = i * 256 + tid;            // vec idx over (h2,wq,co/8): 3584 vecs
    int cv = v & 31, hw = v >> 5;     // hw = h2*56+wq in 0..111
    union { uint4 u; u16 h[8]; } d;
    d.u = *(const uint4*)(src + (long)hw * 256 + cv * 8);
#pragma unroll
    for (int e = 0; e < 8; ++e) t[cv * 8 + e][hw] = d.h[e];
  }
  __syncthreads();
  float* dst = out + (long)n * 200704 + ho * 28;   // + co*784 + wo
#pragma unroll
  for (int i = 0; i < 28; ++i) {
    int oidx = i * 256 + tid;         // 0..7167
    int co = oidx / 28, wo = oidx - co * 28;
    float s = ssc[co], bb = ssb[co];
    int w0 = wo * 2;
    float r0 = fmaxf(s * bf16_f32(t[co][w0])      + bb, 0.f);
    float r1 = fmaxf(s * bf16_f32(t[co][w0 + 1])  + bb, 0.f);
    float r2 = fmaxf(s * bf16_f32(t[co][56 + w0]) + bb, 0.f);
    float r3 = fmaxf(s * bf16_f32(t[co][57 + w0]) + bb, 0.f);
    dst[(long)co * 784 + wo] = fmaxf(fmaxf(r0, r1), fmaxf(r2, r3));
  }
}

extern "C" void kernel_launch(void* const* d_in, const int* in_sizes, int n_in,
                              void* d_out, int out_size, void* d_ws, size_t ws_size,
                              hipStream_t stream) {
  const float* x     = (const float*)d_in[0];
  const float* W     = (const float*)d_in[1];
  const float* gamma = (const float*)d_in[2];
  const float* beta  = (const float*)d_in[3];
  float* out = (float*)d_out;
  char* ws = (char*)d_ws;
  u16*  xp    = (u16*)ws;
  u16*  wp    = (u16*)(ws + WPACK_OFF);
  u16*  yb    = (u16*)(ws + Y_OFF);
  float* stats = (float*)(ws + STATS_OFF);   // sum[256], sumsq[256], scale[256], shift[256]

  hipMemsetAsync(xp, 0, XPAD_BYTES, stream);
  hipMemsetAsync(stats, 0, 512 * sizeof(float), stream);
  hipLaunchKernelGGL(prep_w, dim3(2304), dim3(256), 0, stream, W, wp);
  hipLaunchKernelGGL(prep_x, dim3(32 * 56 * 4), dim3(256), 0, stream, x, xp);
  hipLaunchKernelGGL(conv_gemm, dim3(1568), dim3(256), 0, stream, xp, wp, yb, stats);
  hipLaunchKernelGGL(bn_stats, dim3(1), dim3(256), 0, stream, stats, gamma, beta, stats + 512);
  hipLaunchKernelGGL(bn_pool, dim3(32 * 28), dim3(256), 0, stream, yb, stats + 512, out);
}

// Round 3
// 282.355 us; speedup vs baseline: 1.0802x; 1.0802x over previous
//
#include <hip/hip_runtime.h>
#include <stdint.h>

typedef unsigned short u16;
typedef __bf16 bf16x8 __attribute__((ext_vector_type(8)));
typedef float f32x16 __attribute__((ext_vector_type(16)));

typedef const __attribute__((address_space(1))) void* gptr_t;
typedef __attribute__((address_space(3))) void* sptr_t;

// ---- sizes ----
// x: (32,256,56,56) f32, W: (256,256,3,3) f32, out: (32,256,28,28) f32
#define M_TOTAL    100352          // 32*56*56
#define XPAD_BYTES 55115776L       // 32*58*58*256 * 2
#define WPACK_OFF  55115776L
#define Y_OFF      56295424L       // + 9*256*256*2 = 1179648
#define STATS_OFF  107675648L      // + 32*56*56*256*2 = 51380224

__device__ __forceinline__ u16 f32_bf16(float f) {
  uint32_t u = __float_as_uint(f);
  u += 0x7FFFu + ((u >> 16) & 1u);
  return (u16)(u >> 16);
}
__device__ __forceinline__ float bf16_f32(u16 h) {
  return __uint_as_float(((uint32_t)h) << 16);
}
__device__ __forceinline__ void gload_lds16(const void* g, void* l) {
  __builtin_amdgcn_global_load_lds((gptr_t)g, (sptr_t)l, 16, 0, 0);
}

// ---- binarize + pack W:  wp[((f*32+cg)*256 + co)*8 + e] = sign(W[co][ci][kh][kw])
//      ci = cg*8 + e;  B operand [K][co] in 8-channel slices
__global__ void prep_w(const float* __restrict__ W, u16* __restrict__ wp) {
  int idx = blockIdx.x * 256 + threadIdx.x;       // 0..589823
  int e  = idx & 7;
  int co = (idx >> 3) & 255;
  int ks = idx >> 11;                             // f*32 + cg
  int f  = ks >> 5;
  int ci = ((ks & 31) << 3) | e;
  int kh = (f * 11) >> 5;                         // f/3 for f in 0..8
  int kw = f - kh * 3;
  float v = W[((co * 256 + ci) * 3 + kh) * 3 + kw];
  wp[idx] = (u16)(0x3F80u | ((__float_as_uint(v) >> 16) & 0x8000u));
}

// ---- NCHW f32 -> padded NHWC bf16  (x_pad[32][58][58][256], borders pre-zeroed by memset)
__global__ void prep_x(const float* __restrict__ x, u16* __restrict__ xp) {
  int b = blockIdx.x;                 // (n*56 + h)*4 + cblk
  int cblk = b & 3;
  int nh = b >> 2;
  int h = nh % 56, n = nh / 56;
  __shared__ float tile[64][57];
  int tid = threadIdx.x;
  const float* src = x + (((long)n * 256 + cblk * 64) * 56 + h) * 56;
#pragma unroll
  for (int i = 0; i < 14; ++i) {
    int idx = i * 256 + tid;          // 0..3583
    int c = idx / 56, wq = idx - c * 56;
    tile[c][wq] = src[(long)c * 3136 + wq];
  }
  __syncthreads();
  u16* dst = xp + (((long)n * 58 + (h + 1)) * 58 + 1) * 256 + cblk * 64;
#pragma unroll
  for (int i = 0; i < 14; ++i) {
    int idx = i * 256 + tid;
    int c = idx & 63, wq = idx >> 6;  // wq 0..55
    dst[(long)wq * 256 + c] = f32_bf16(tile[c][wq]);
  }
}

// ---- implicit-GEMM conv: BM=256, BN=256, BK=32, 8 waves, 32x32x16 MFMA,
//      3-stage counted-vmcnt pipeline. y[M][256] bf16; per-channel sum/sumsq atomics.
__global__ __launch_bounds__(512, 2) void conv_gemm(
    const u16* __restrict__ xp, const u16* __restrict__ wp,
    u16* __restrict__ y, float* __restrict__ stats) {
  // k-sliced layout: [buf][kslot(4)][row(256)][8 bf16] -> gload_lds-linear, conflict-free
  __shared__ __align__(16) u16 As[3][4][256][8];   // 48 KB
  __shared__ __align__(16) u16 Bs[3][4][256][8];   // 48 KB

  const int tid = threadIdx.x;
  const int w = tid >> 6, l = tid & 63;
  const int gm = blockIdx.x;                       // 392 M-tiles, N fits one 256 tile

  // ---- staging addresses: thread owns (row = tid&255, kslot = (tid>>8) + 2i) for issue i
  const int r = tid & 255;
  const int gr = gm * 256 + r;
  const int n   = gr / 3136;
  const int rem = gr - n * 3136;
  const int hh  = rem / 56;
  const int wx  = rem - hh * 56;
  const u16* gA = xp + (((long)n * 58 + hh) * 58 + wx) * 256 + ((tid >> 8) << 3);
  const u16* gB = wp + tid * 8;
  // wave-uniform LDS dest (HW adds lane*16B): byte = buf*16384 + i*8192 + w*1024
  u16* ldsA0 = &As[0][0][0][0] + w * 512;
  u16* ldsB0 = &Bs[0][0][0][0] + w * 512;

  auto stage = [&](int buf, int t) {
    const int f = t >> 3, cc = t & 7;              // t = f*8 + cc, 72 K-tiles
    const int kh = (f * 11) >> 5;
    const int kw = f - kh * 3;
    const int aoff = (kh * 58 + kw) * 256 + cc * 32;
    const u16* ga = gA + aoff;
    const u16* gb = gB + t * 8192;
    u16* la = ldsA0 + buf * 8192;
    u16* lb = ldsB0 + buf * 8192;
    gload_lds16(ga,        la);                    // kslots 0..1
    gload_lds16(ga + 16,   la + 4096);             // kslots 2..3
    gload_lds16(gb,        lb);
    gload_lds16(gb + 4096, lb + 4096);
  };

  // ---- fragment coords: wave tile 128x64 = 4rb x 2cb of 32x32
  const int wm = w >> 2, wn = w & 3;
  const int l31 = l & 31, lh = l >> 5;
  const int rowA = wm * 128 + l31;                 // + rb*32
  const int rowB = wn * 64 + l31;                  // + cb*32

  f32x16 acc[4][2] = {};

  stage(0, 0);
  stage(1, 1);

  int buf = 0;
  for (int t = 0; t < 72; ++t) {
    int sb = buf + 2; if (sb >= 3) sb -= 3;
    if (t + 2 < 72) stage(sb, t + 2);
    // each stage = 4 gload_lds per wave. Wait tile t's 4 (oldest); keep newer in flight.
    if (t + 2 < 72)      asm volatile("s_waitcnt vmcnt(8)" ::: "memory");
    else if (t + 1 < 72) asm volatile("s_waitcnt vmcnt(4)" ::: "memory");
    else                 asm volatile("s_waitcnt vmcnt(0)" ::: "memory");
    __builtin_amdgcn_s_barrier();
    asm volatile("" ::: "memory");

    bf16x8 av[4][2], bv[2][2];
#pragma unroll
    for (int kc = 0; kc < 2; ++kc) {
#pragma unroll
      for (int rb = 0; rb < 4; ++rb)
        av[rb][kc] = *(const bf16x8*)&As[buf][kc * 2 + lh][rowA + rb * 32][0];
#pragma unroll
      for (int cb = 0; cb < 2; ++cb)
        bv[cb][kc] = *(const bf16x8*)&Bs[buf][kc * 2 + lh][rowB + cb * 32][0];
    }
    __builtin_amdgcn_s_setprio(1);
#pragma unroll
    for (int kc = 0; kc < 2; ++kc)
#pragma unroll
      for (int rb = 0; rb < 4; ++rb)
#pragma unroll
        for (int cb = 0; cb < 2; ++cb)
          acc[rb][cb] = __builtin_amdgcn_mfma_f32_32x32x16_bf16(
              av[rb][kc], bv[cb][kc], acc[rb][cb], 0, 0, 0);
    __builtin_amdgcn_s_setprio(0);
    // all this wave's ds_reads retired before other waves may overwrite buf
    asm volatile("s_waitcnt lgkmcnt(0)" ::: "memory");
    __builtin_amdgcn_s_barrier();
    asm volatile("" ::: "memory");
    buf = buf + 1; if (buf >= 3) buf = 0;
  }

  // ---- per-channel partial sums -> atomics (C col = lane&31; lane and lane+32 same col)
#pragma unroll
  for (int cb = 0; cb < 2; ++cb) {
    float s = 0.f, q = 0.f;
#pragma unroll
    for (int rb = 0; rb < 4; ++rb)
#pragma unroll
      for (int j = 0; j < 16; ++j) {
        float v = acc[rb][cb][j];
        s += v; q += v * v;
      }
    s += __shfl_xor(s, 32, 64);
    q += __shfl_xor(q, 32, 64);
    if (lh == 0) {
      int col = wn * 64 + cb * 32 + l31;
      atomicAdd(&stats[col], s);
      atomicAdd(&stats[256 + col], q);
    }
  }

  // ---- store y bf16: row = (reg&3) + 8*(reg>>2) + 4*lh, col = lane&31
  const long rbase = (long)gm * 256 + wm * 128;
#pragma unroll
  for (int rb = 0; rb < 4; ++rb)
#pragma unroll
    for (int j = 0; j < 16; ++j) {
      long rr = rbase + rb * 32 + (j & 3) + 8 * (j >> 2) + 4 * lh;
      u16* dst = y + rr * 256 + wn * 64 + l31;
      dst[0]  = f32_bf16(acc[rb][0][j]);
      dst[32] = f32_bf16(acc[rb][1][j]);
    }
}

// ---- finalize BN coefficients: scale = gamma*rsqrt(var+eps), shift = beta - mean*scale
__global__ void bn_stats(const float* __restrict__ stats, const float* __restrict__ gamma,
                         const float* __restrict__ beta, float* __restrict__ sc) {
  int c = threadIdx.x;
  const float inv = 1.0f / (float)M_TOTAL;
  float mean = stats[c] * inv;
  float var  = stats[256 + c] * inv - mean * mean;
  float s = gamma[c] * rsqrtf(var + 1e-5f);
  float b = beta[c] - mean * s;
  sc[c] = s;
  sc[256 + c] = b;
}

// ---- fused BN + ReLU + 2x2 maxpool, NHWC bf16 -> NCHW f32 ----
__global__ void bn_pool(const u16* __restrict__ y, const float* __restrict__ sc,
                        float* __restrict__ out) {
  int b = blockIdx.x;                 // n*28 + ho
  int ho = b % 28, n = b / 28;
  __shared__ u16 t[256][113];         // [co][h2*56+wq], pad to break conflicts
  __shared__ float ssc[256], ssb[256];
  int tid = threadIdx.x;
  ssc[tid] = sc[tid];
  ssb[tid] = sc[256 + tid];
  const u16* src = y + (((long)n * 56 + ho * 2) * 56) * 256;
#pragma unroll
  for (int i = 0; i < 14; ++i) {
    int v = i * 256 + tid;            // vec idx over (h2,wq,co/8): 3584 vecs
    int cv = v & 31, hw = v >> 5;     // hw = h2*56+wq in 0..111
    union { uint4 u; u16 h[8]; } d;
    d.u = *(const uint4*)(src + (long)hw * 256 + cv * 8);
#pragma unroll
    for (int e = 0; e < 8; ++e) t[cv * 8 + e][hw] = d.h[e];
  }
  __syncthreads();
  float* dst = out + (long)n * 200704 + ho * 28;   // + co*784 + wo
#pragma unroll
  for (int i = 0; i < 28; ++i) {
    int oidx = i * 256 + tid;         // 0..7167
    int co = oidx / 28, wo = oidx - co * 28;
    float s = ssc[co], bb = ssb[co];
    int w0 = wo * 2;
    float r0 = fmaxf(s * bf16_f32(t[co][w0])      + bb, 0.f);
    float r1 = fmaxf(s * bf16_f32(t[co][w0 + 1])  + bb, 0.f);
    float r2 = fmaxf(s * bf16_f32(t[co][56 + w0]) + bb, 0.f);
    float r3 = fmaxf(s * bf16_f32(t[co][57 + w0]) + bb, 0.f);
    dst[(long)co * 784 + wo] = fmaxf(fmaxf(r0, r1), fmaxf(r2, r3));
  }
}

extern "C" void kernel_launch(void* const* d_in, const int* in_sizes, int n_in,
                              void* d_out, int out_size, void* d_ws, size_t ws_size,
                              hipStream_t stream) {
  const float* x     = (const float*)d_in[0];
  const float* W     = (const float*)d_in[1];
  const float* gamma = (const float*)d_in[2];
  const float* beta  = (const float*)d_in[3];
  float* out = (float*)d_out;
  char* ws = (char*)d_ws;
  u16*  xp    = (u16*)ws;
  u16*  wp    = (u16*)(ws + WPACK_OFF);
  u16*  yb    = (u16*)(ws + Y_OFF);
  float* stats = (float*)(ws + STATS_OFF);   // sum[256], sumsq[256], scale[256], shift[256]

  hipMemsetAsync(xp, 0, XPAD_BYTES, stream);
  hipMemsetAsync(stats, 0, 512 * sizeof(float), stream);
  hipLaunchKernelGGL(prep_w, dim3(2304), dim3(256), 0, stream, W, wp);
  hipLaunchKernelGGL(prep_x, dim3(32 * 56 * 4), dim3(256), 0, stream, x, xp);
  hipLaunchKernelGGL(conv_gemm, dim3(392), dim3(512), 0, stream, xp, wp, yb, stats);
  hipLaunchKernelGGL(bn_stats, dim3(1), dim3(256), 0, stream, stats, gamma, beta, stats + 512);
  hipLaunchKernelGGL(bn_pool, dim3(32 * 28), dim3(256), 0, stream, yb, stats + 512, out);
}

// Round 4
// 238.824 us; speedup vs baseline: 1.2771x; 1.1823x over previous
//
#include <hip/hip_runtime.h>
#include <stdint.h>

typedef unsigned short u16;
typedef __bf16 bf16x8 __attribute__((ext_vector_type(8)));
typedef float f32x16 __attribute__((ext_vector_type(16)));

typedef const __attribute__((address_space(1))) void* gptr_t;
typedef __attribute__((address_space(3))) void* sptr_t;

// ---- sizes ----
// x: (32,256,56,56) f32, W: (256,256,3,3) f32, out: (32,256,28,28) f32
#define M_TOTAL    100352          // 32*56*56
#define XPAD_BYTES 55115776L       // 32*58*58*256 * 2
#define WPACK_OFF  55115776L
#define Y_OFF      56295424L       // + 9*256*256*2 = 1179648
#define STATS_OFF  107675648L      // + 32*56*56*256*2 = 51380224

__device__ __forceinline__ u16 f32_bf16(float f) {
  uint32_t u = __float_as_uint(f);
  u += 0x7FFFu + ((u >> 16) & 1u);
  return (u16)(u >> 16);
}
__device__ __forceinline__ float bf16_f32(u16 h) {
  return __uint_as_float(((uint32_t)h) << 16);
}
__device__ __forceinline__ void gload_lds16(const void* g, void* l) {
  __builtin_amdgcn_global_load_lds((gptr_t)g, (sptr_t)l, 16, 0, 0);
}

// ---- binarize + pack W:  wp[((f*32+cg)*256 + co)*8 + e] = sign(W[co][ci][kh][kw])
//      ci = cg*8 + e;  B operand [K][co] in 8-channel slices
__global__ void prep_w(const float* __restrict__ W, u16* __restrict__ wp) {
  int idx = blockIdx.x * 256 + threadIdx.x;       // 0..589823
  int e  = idx & 7;
  int co = (idx >> 3) & 255;
  int ks = idx >> 11;                             // f*32 + cg
  int f  = ks >> 5;
  int ci = ((ks & 31) << 3) | e;
  int kh = (f * 11) >> 5;                         // f/3 for f in 0..8
  int kw = f - kh * 3;
  float v = W[((co * 256 + ci) * 3 + kh) * 3 + kw];
  wp[idx] = (u16)(0x3F80u | ((__float_as_uint(v) >> 16) & 0x8000u));
}

// ---- NCHW f32 -> padded NHWC bf16  (x_pad[32][58][58][256], borders pre-zeroed by memset)
__global__ void prep_x(const float* __restrict__ x, u16* __restrict__ xp) {
  int b = blockIdx.x;                 // (n*56 + h)*4 + cblk
  int cblk = b & 3;
  int nh = b >> 2;
  int h = nh % 56, n = nh / 56;
  __shared__ float tile[64][57];
  int tid = threadIdx.x;
  const float* src = x + (((long)n * 256 + cblk * 64) * 56 + h) * 56;
#pragma unroll
  for (int i = 0; i < 14; ++i) {
    int idx = i * 256 + tid;          // 0..3583
    int c = idx / 56, wq = idx - c * 56;
    tile[c][wq] = src[(long)c * 3136 + wq];
  }
  __syncthreads();
  u16* dst = xp + (((long)n * 58 + (h + 1)) * 58 + 1) * 256 + cblk * 64;
#pragma unroll
  for (int i = 0; i < 14; ++i) {
    int idx = i * 256 + tid;
    int c = idx & 63, wq = idx >> 6;  // wq 0..55
    dst[(long)wq * 256 + c] = f32_bf16(tile[c][wq]);
  }
}

// ---- implicit-GEMM conv: BM=128, BN=256, BK=32, 4 waves (wave tile 128x64),
//      3-stage counted-vmcnt pipeline, 2 blocks/CU. Same sync structure as R3.
__global__ __launch_bounds__(256, 2) void conv_gemm(
    const u16* __restrict__ xp, const u16* __restrict__ wp,
    u16* __restrict__ y, float* __restrict__ stats) {
  // k-sliced layout: [buf][kslot(4)][row][8 bf16] -> gload_lds-linear, conflict-free
  __shared__ __align__(16) u16 As[3][4][128][8];   // 24 KB
  __shared__ __align__(16) u16 Bs[3][4][256][8];   // 48 KB

  const int tid = threadIdx.x;
  const int w = tid >> 6, l = tid & 63;
  const int gm = blockIdx.x;                       // 784 M-tiles, N fits one 256 tile

  // ---- A staging: wave w, issue j -> chunk c=j*4+w: kslot=j*2+(w>>1), rows (w&1)*64+l
  const int gr = gm * 128 + ((w & 1) << 6) + l;
  const int n   = gr / 3136;
  const int rem = gr - n * 3136;
  const int hh  = rem / 56;
  const int wx  = rem - hh * 56;
  const u16* gA = xp + (((long)n * 58 + hh) * 58 + wx) * 256 + ((w >> 1) << 3);
  // ---- B staging: wave w, issue i -> kslot=i, cols w*64+l
  const u16* gB = wp + ((w << 6) + l) * 8;
  // wave-uniform LDS dests (HW adds lane*16B)
  u16* ldsA0 = &As[0][0][0][0] + w * 512;          // +buf*4096 +j*2048
  u16* ldsB0 = &Bs[0][0][0][0] + w * 512;          // +buf*8192 +i*2048

  auto stage = [&](int buf, int t) {
    const int f = t >> 3, cc = t & 7;              // t = f*8 + cc, 72 K-tiles
    const int kh = (f * 11) >> 5;
    const int kw = f - kh * 3;
    const int aoff = (kh * 58 + kw) * 256 + cc * 32;
    const u16* ga = gA + aoff;
    const u16* gb = gB + t * 8192;
    u16* la = ldsA0 + buf * 4096;
    u16* lb = ldsB0 + buf * 8192;
    gload_lds16(ga,       la);                     // kslot (w>>1)
    gload_lds16(ga + 16,  la + 2048);              // kslot 2+(w>>1)
    gload_lds16(gb,            lb);                // kslot 0
    gload_lds16(gb + 2048,     lb + 2048);         // kslot 1
    gload_lds16(gb + 4096,     lb + 4096);         // kslot 2
    gload_lds16(gb + 6144,     lb + 6144);         // kslot 3
  };

  // ---- fragment coords: wave tile 128x64: rows rb*32+l31 (rb 0..3), cols w*64+cb*32+l31
  const int l31 = l & 31, lh = l >> 5;

  f32x16 acc[4][2] = {};

  stage(0, 0);
  stage(1, 1);

  int buf = 0;
  for (int t = 0; t < 72; ++t) {
    int sb = buf + 2; if (sb >= 3) sb -= 3;
    if (t + 2 < 72) stage(sb, t + 2);
    // each stage = 6 gload_lds per wave. Wait tile t's 6 (oldest); keep newer in flight.
    if (t + 2 < 72)      asm volatile("s_waitcnt vmcnt(12)" ::: "memory");
    else if (t + 1 < 72) asm volatile("s_waitcnt vmcnt(6)"  ::: "memory");
    else                 asm volatile("s_waitcnt vmcnt(0)"  ::: "memory");
    __builtin_amdgcn_s_barrier();
    asm volatile("" ::: "memory");

    bf16x8 av[4][2], bv[2][2];
#pragma unroll
    for (int kc = 0; kc < 2; ++kc) {
#pragma unroll
      for (int rb = 0; rb < 4; ++rb)
        av[rb][kc] = *(const bf16x8*)&As[buf][kc * 2 + lh][rb * 32 + l31][0];
#pragma unroll
      for (int cb = 0; cb < 2; ++cb)
        bv[cb][kc] = *(const bf16x8*)&Bs[buf][kc * 2 + lh][(w << 6) + cb * 32 + l31][0];
    }
    __builtin_amdgcn_s_setprio(1);
#pragma unroll
    for (int kc = 0; kc < 2; ++kc)
#pragma unroll
      for (int rb = 0; rb < 4; ++rb)
#pragma unroll
        for (int cb = 0; cb < 2; ++cb)
          acc[rb][cb] = __builtin_amdgcn_mfma_f32_32x32x16_bf16(
              av[rb][kc], bv[cb][kc], acc[rb][cb], 0, 0, 0);
    __builtin_amdgcn_s_setprio(0);
    // all this wave's ds_reads retired before any wave re-stages this buf (next iter)
    asm volatile("s_waitcnt lgkmcnt(0)" ::: "memory");
    __builtin_amdgcn_s_barrier();
    asm volatile("" ::: "memory");
    buf = buf + 1; if (buf >= 3) buf = 0;
  }

  // ---- per-channel partial sums -> atomics (C col = lane&31; lane and lane+32 same col)
#pragma unroll
  for (int cb = 0; cb < 2; ++cb) {
    float s = 0.f, q = 0.f;
#pragma unroll
    for (int rb = 0; rb < 4; ++rb)
#pragma unroll
      for (int j = 0; j < 16; ++j) {
        float v = acc[rb][cb][j];
        s += v; q += v * v;
      }
    s += __shfl_xor(s, 32, 64);
    q += __shfl_xor(q, 32, 64);
    if (lh == 0) {
      int col = (w << 6) + cb * 32 + l31;
      atomicAdd(&stats[col], s);
      atomicAdd(&stats[256 + col], q);
    }
  }

  // ---- store y bf16: row = (reg&3) + 8*(reg>>2) + 4*lh, col = lane&31
  const long rbase = (long)gm * 128;
#pragma unroll
  for (int rb = 0; rb < 4; ++rb)
#pragma unroll
    for (int j = 0; j < 16; ++j) {
      long rr = rbase + rb * 32 + (j & 3) + 8 * (j >> 2) + 4 * lh;
      u16* dst = y + rr * 256 + (w << 6) + l31;
      dst[0]  = f32_bf16(acc[rb][0][j]);
      dst[32] = f32_bf16(acc[rb][1][j]);
    }
}

// ---- finalize BN coefficients: scale = gamma*rsqrt(var+eps), shift = beta - mean*scale
__global__ void bn_stats(const float* __restrict__ stats, const float* __restrict__ gamma,
                         const float* __restrict__ beta, float* __restrict__ sc) {
  int c = threadIdx.x;
  const float inv = 1.0f / (float)M_TOTAL;
  float mean = stats[c] * inv;
  float var  = stats[256 + c] * inv - mean * mean;
  float s = gamma[c] * rsqrtf(var + 1e-5f);
  float b = beta[c] - mean * s;
  sc[c] = s;
  sc[256 + c] = b;
}

// ---- fused BN + ReLU + 2x2 maxpool, NHWC bf16 -> NCHW f32 ----
__global__ void bn_pool(const u16* __restrict__ y, const float* __restrict__ sc,
                        float* __restrict__ out) {
  int b = blockIdx.x;                 // n*28 + ho
  int ho = b % 28, n = b / 28;
  __shared__ u16 t[256][113];         // [co][h2*56+wq], pad to break conflicts
  __shared__ float ssc[256], ssb[256];
  int tid = threadIdx.x;
  ssc[tid] = sc[tid];
  ssb[tid] = sc[256 + tid];
  const u16* src = y + (((long)n * 56 + ho * 2) * 56) * 256;
#pragma unroll
  for (int i = 0; i < 14; ++i) {
    int v = i * 256 + tid;            // vec idx over (h2,wq,co/8): 3584 vecs
    int cv = v & 31, hw = v >> 5;     // hw = h2*56+wq in 0..111
    union { uint4 u; u16 h[8]; } d;
    d.u = *(const uint4*)(src + (long)hw * 256 + cv * 8);
#pragma unroll
    for (int e = 0; e < 8; ++e) t[cv * 8 + e][hw] = d.h[e];
  }
  __syncthreads();
  float* dst = out + (long)n * 200704 + ho * 28;   // + co*784 + wo
#pragma unroll
  for (int i = 0; i < 28; ++i) {
    int oidx = i * 256 + tid;         // 0..7167
    int co = oidx / 28, wo = oidx - co * 28;
    float s = ssc[co], bb = ssb[co];
    int w0 = wo * 2;
    float r0 = fmaxf(s * bf16_f32(t[co][w0])      + bb, 0.f);
    float r1 = fmaxf(s * bf16_f32(t[co][w0 + 1])  + bb, 0.f);
    float r2 = fmaxf(s * bf16_f32(t[co][56 + w0]) + bb, 0.f);
    float r3 = fmaxf(s * bf16_f32(t[co][57 + w0]) + bb, 0.f);
    dst[(long)co * 784 + wo] = fmaxf(fmaxf(r0, r1), fmaxf(r2, r3));
  }
}

extern "C" void kernel_launch(void* const* d_in, const int* in_sizes, int n_in,
                              void* d_out, int out_size, void* d_ws, size_t ws_size,
                              hipStream_t stream) {
  const float* x     = (const float*)d_in[0];
  const float* W     = (const float*)d_in[1];
  const float* gamma = (const float*)d_in[2];
  const float* beta  = (const float*)d_in[3];
  float* out = (float*)d_out;
  char* ws = (char*)d_ws;
  u16*  xp    = (u16*)ws;
  u16*  wp    = (u16*)(ws + WPACK_OFF);
  u16*  yb    = (u16*)(ws + Y_OFF);
  float* stats = (float*)(ws + STATS_OFF);   // sum[256], sumsq[256], scale[256], shift[256]

  hipMemsetAsync(xp, 0, XPAD_BYTES, stream);
  hipMemsetAsync(stats, 0, 512 * sizeof(float), stream);
  hipLaunchKernelGGL(prep_w, dim3(2304), dim3(256), 0, stream, W, wp);
  hipLaunchKernelGGL(prep_x, dim3(32 * 56 * 4), dim3(256), 0, stream, x, xp);
  hipLaunchKernelGGL(conv_gemm, dim3(784), dim3(256), 0, stream, xp, wp, yb, stats);
  hipLaunchKernelGGL(bn_stats, dim3(1), dim3(256), 0, stream, stats, gamma, beta, stats + 512);
  hipLaunchKernelGGL(bn_pool, dim3(32 * 28), dim3(256), 0, stream, yb, stats + 512, out);
}